// Round 4
// baseline (831.315 us; speedup 1.0000x reference)
//
#include <hip/hip_runtime.h>
#include <hip/hip_bf16.h>

#define NN 100000
#define EE 500000

typedef __attribute__((ext_vector_type(8))) short short8v;
typedef __attribute__((ext_vector_type(4))) float f32x4;

__device__ __forceinline__ short f2bf(float f) {
  unsigned u = __builtin_bit_cast(unsigned, f);
  u += 0x7fffu + ((u >> 16) & 1u);
  return (short)(u >> 16);
}
__device__ __forceinline__ float bf2f(short s) {
  unsigned u = ((unsigned)(unsigned short)s) << 16;
  return __builtin_bit_cast(float, u);
}

// ---------------- K0: weights -> bf16 fragment layouts + permuted tw/tb -----
// Btfrag: ((cb*8 + strip)*4 + kt)*512 + lane*8 + b ; W_cb[k][c],
//   k = kt*32 + (lane>>4)*8 + b, c = strip*16 + (lane&15)
// Wefrag: (strip*8 + kt)*512 + lane*8 + b ; We[k][c], same k/c mapping
// twp/tbp[r][cphys]: tw[((cphys>>3)^r)*8 + (cphys&7)]  (chunk-XOR permuted)
__global__ __launch_bounds__(256) void k_prep(
    const float* __restrict__ Wq, const float* __restrict__ Wk,
    const float* __restrict__ Wv, const float* __restrict__ Wsk,
    const float* __restrict__ We, const float* __restrict__ tw,
    const float* __restrict__ tb,
    short* __restrict__ Btfrag, short* __restrict__ Wefrag,
    float* __restrict__ twp, float* __restrict__ tbp)
{
  int idx = blockIdx.x * 256 + threadIdx.x;
  if (idx < 65536) {
    int b = idx & 7, lane = (idx >> 3) & 63, kt = (idx >> 9) & 3, tn = (idx >> 11) & 7, cb = idx >> 14;
    int k = kt * 32 + (lane >> 4) * 8 + b;
    int c = tn * 16 + (lane & 15);
    const float* W = cb == 0 ? Wq : cb == 1 ? Wk : cb == 2 ? Wv : Wsk;
    Btfrag[idx] = f2bf(W[k * 128 + c]);
  } else if (idx < 98304) {
    int i2 = idx - 65536;
    int b = i2 & 7, lane = (i2 >> 3) & 63, kt = (i2 >> 9) & 7, strip = i2 >> 12;
    int k = kt * 32 + (lane >> 4) * 8 + b;
    int c = strip * 16 + (lane & 15);
    Wefrag[i2] = f2bf(We[k * 128 + c]);
  } else if (idx < 100352) {
    int i3 = idx - 98304;
    int which = i3 >> 10;
    int r = (i3 >> 7) & 7;
    int c = i3 & 127;
    int lc = ((c >> 3) ^ r) * 8 + (c & 7);
    if (which) tbp[r * 128 + c] = tb[lc];
    else       twp[r * 128 + c] = tw[lc];
  }
}

// ---------------- K1: x -> bf16 ---------------------------------------------
__global__ __launch_bounds__(256) void k_xcast(const float* __restrict__ x,
                                               unsigned short* __restrict__ xb)
{
  size_t base = ((size_t)blockIdx.x * 256 + threadIdx.x) * 8;
  f32x4 a = *(const f32x4*)(x + base);
  f32x4 b = *(const f32x4*)(x + base + 4);
  short8v w;
  #pragma unroll
  for (int j = 0; j < 4; ++j) { w[j] = f2bf(a[j]); w[4 + j] = f2bf(b[j]); }
  *(short8v*)(xb + base) = w;
}

__global__ __launch_bounds__(256) void k_zero(int* __restrict__ p, int n)
{
  int i = blockIdx.x * 256 + threadIdx.x;
  if (i < n) p[i] = 0;
}

// ---------------- counting sort by dst --------------------------------------
__global__ __launch_bounds__(256) void k_hist(const int* __restrict__ ei, int* __restrict__ cnt)
{
  int e = blockIdx.x * 256 + threadIdx.x;
  if (e < EE) atomicAdd(&cnt[ei[EE + e]], 1);
}

__global__ __launch_bounds__(256) void k_scan_a(const int* __restrict__ cnt,
    int* __restrict__ offtmp, int* __restrict__ bsum)
{
  __shared__ int sc[256];
  int t = threadIdx.x;
  int i = blockIdx.x * 256 + t;
  int v = (i < NN) ? cnt[i] : 0;
  sc[t] = v;
  __syncthreads();
  for (int d = 1; d < 256; d <<= 1) {
    int add = (t >= d) ? sc[t - d] : 0;
    __syncthreads();
    sc[t] += add;
    __syncthreads();
  }
  if (i < NN) offtmp[i] = sc[t] - v;
  if (t == 255) bsum[blockIdx.x] = sc[255];
}

__global__ __launch_bounds__(512) void k_scan_b(const int* __restrict__ bsum,
                                                int* __restrict__ bbase)
{
  __shared__ int sc[512];
  int t = threadIdx.x;
  int v = (t < 391) ? bsum[t] : 0;
  sc[t] = v;
  __syncthreads();
  for (int d = 1; d < 512; d <<= 1) {
    int add = (t >= d) ? sc[t - d] : 0;
    __syncthreads();
    sc[t] += add;
    __syncthreads();
  }
  bbase[t] = sc[t] - v;
}

__global__ __launch_bounds__(256) void k_scatter(const int* __restrict__ ei,
    const int* __restrict__ offtmp, const int* __restrict__ bbase,
    int* __restrict__ cur, int* __restrict__ sorted)
{
  int e = blockIdx.x * 256 + threadIdx.x;
  if (e < EE) {
    int d = ei[EE + e];
    int pos = offtmp[d] + bbase[d >> 8] + atomicAdd(&cur[d], 1);
    sorted[pos] = e;
  }
}

// ---------------- K_emeta: pack per-edge meta in sorted order ---------------
__global__ __launch_bounds__(256) void k_emeta(const int* __restrict__ ei,
    const float* __restrict__ tt, const float* __restrict__ lu,
    const int* __restrict__ sorted, int4* __restrict__ emeta)
{
  int i = blockIdx.x * 256 + threadIdx.x;
  if (i < EE) {
    int eid = sorted[i];
    int sv = ei[eid];
    int4 m;
    m.x = eid; m.y = sv; m.z = ei[EE + eid];
    m.w = __float_as_int(tt[eid] - lu[sv]);
    emeta[i] = m;
  }
}

// ---------------- K_main: 32 dst nodes/block, 64-edge tiles, swizzled LDS ---
__global__ __launch_bounds__(512, 4) void k_main(
    const unsigned short* __restrict__ xb, const float* __restrict__ msg,
    const float* __restrict__ twp, const float* __restrict__ tbp,
    const short* __restrict__ Btfrag, const short* __restrict__ Wefrag,
    const float* __restrict__ bq, const float* __restrict__ bk,
    const float* __restrict__ bv, const float* __restrict__ bsk,
    const int* __restrict__ offtmp, const int* __restrict__ bbase,
    const int4* __restrict__ emeta, float* __restrict__ out)
{
  __shared__ short XS[64 * 128];    // x[src] bf16, chunk-swizzled rows
  __shared__ short MS[64 * 128];    // msg bf16, swizzled
  __shared__ short TEs[64 * 128];   // time enc bf16, swizzled
  __shared__ short QL[32 * 128];    // q bf16 per owned node
  __shared__ float accum[32 * 133]; // f32 numerator
  __shared__ float pdot[128];       // [head][64 edge rows] raw dot
  __shared__ float sden[64];        // [32 nodes][2 heads]
  __shared__ int dslot[64];

  const int tid = threadIdx.x;
  const int nb0 = blockIdx.x * 32;
  const int wid = tid >> 6, lane = tid & 63;
  const int g = lane >> 4, lr = lane & 15, l7 = lr & 7;
  const int el = tid >> 3, p = tid & 7;
  const int r7 = el & 7;
  const int pl = p ^ r7;             // logical chunk staged by this thread
  const int cme = wid * 16 + lr;     // this wave's output column
  const int hme = wid >> 2;          // head of this wave

  for (int i = tid; i < 32 * 133; i += 512) accum[i] = 0.f;
  if (tid < 64) sden[tid] = 0.f;

  const float bqc = bq[cme], bkc = bk[cme], bvc = bv[cme], bskc = bsk[cme];

  // stage owned nodes' x (rows 0..31), swizzled: physical chunk p <- logical pl
  if (el < 32) {
    int node = nb0 + el;             // NN % 32 == 0 -> always valid
    const unsigned short* xp = xb + (size_t)node * 128;
    short8v a = *(const short8v*)(xp + pl * 8);
    short8v b = *(const short8v*)(xp + pl * 8 + 64);
    *(short8v*)&XS[el * 128 + p * 8] = a;
    *(short8v*)&XS[el * 128 + p * 8 + 64] = b;
  }
  __syncthreads();

  // prologue: q -> QL (bf16), skip -> regs (f32)
  f32x4 skacc[2];
  {
    f32x4 qacc[2];
    qacc[0] = (f32x4){0.f, 0.f, 0.f, 0.f}; qacc[1] = qacc[0];
    skacc[0] = qacc[0]; skacc[1] = qacc[0];
    #pragma unroll
    for (int kt = 0; kt < 4; ++kt) {
      short8v bqf = *(const short8v*)(Btfrag + (size_t)(((0 + wid) * 4 + kt) * 64 + lane) * 8);
      short8v bsf = *(const short8v*)(Btfrag + (size_t)(((24 + wid) * 4 + kt) * 64 + lane) * 8);
      const int sw = (((kt << 2) | g) ^ l7) << 3;
      #pragma unroll
      for (int eg = 0; eg < 2; ++eg) {
        const short8v a = *(const short8v*)&XS[(eg * 16 + lr) * 128 + sw];
        qacc[eg] = __builtin_amdgcn_mfma_f32_16x16x32_bf16(a, bqf, qacc[eg], 0, 0, 0);
        skacc[eg] = __builtin_amdgcn_mfma_f32_16x16x32_bf16(a, bsf, skacc[eg], 0, 0, 0);
      }
    }
    #pragma unroll
    for (int eg = 0; eg < 2; ++eg)
      #pragma unroll
      for (int rg = 0; rg < 4; ++rg)
        QL[(eg * 16 + g * 4 + rg) * 128 + cme] = f2bf(qacc[eg][rg] + bqc);
  }

  const int beg = offtmp[nb0] + bbase[nb0 >> 8];
  const int end = (nb0 + 32 < NN) ? (offtmp[nb0 + 32] + bbase[(nb0 + 32) >> 8]) : EE;

  // prefetch tile 0
  int pdst = 0; float prelt = 0.f; bool pval = false;
  short8v px0 = {0,0,0,0,0,0,0,0}, px1 = px0, pmb0 = px0, pmb1 = px0;
  {
    int i = beg + el;
    pval = i < end;
    if (pval) {
      int4 m = emeta[i];
      pdst = m.z; prelt = __int_as_float(m.w);
      const unsigned short* xp = xb + (size_t)m.y * 128 + pl * 8;
      px0 = *(const short8v*)xp;
      px1 = *(const short8v*)(xp + 64);
      const float* mp = msg + (size_t)m.x * 128 + pl * 8;
      f32x4 m0 = *(const f32x4*)mp,        m1 = *(const f32x4*)(mp + 4);
      f32x4 m2 = *(const f32x4*)(mp + 64), m3 = *(const f32x4*)(mp + 68);
      #pragma unroll
      for (int j = 0; j < 4; ++j) {
        pmb0[j] = f2bf(m0[j]); pmb0[4 + j] = f2bf(m1[j]);
        pmb1[j] = f2bf(m2[j]); pmb1[4 + j] = f2bf(m3[j]);
      }
    }
  }
  __syncthreads();   // QL visible; XS free for edge tiles

  for (int t0 = beg; t0 < end; t0 += 64) {
    // ---- S0: commit prefetched tile (swizzled), zero pdot, meta
    short8v wef[8];
    #pragma unroll
    for (int kt = 0; kt < 8; ++kt)
      wef[kt] = *(const short8v*)(Wefrag + (size_t)((wid * 8 + kt) * 64 + lane) * 8);
    if (tid < 128) pdot[tid] = 0.f;
    if (p == 0) dslot[el] = pval ? (pdst - nb0) : -1;
    *(short8v*)&XS[el * 128 + p * 8] = px0;
    *(short8v*)&XS[el * 128 + p * 8 + 64] = px1;
    *(short8v*)&MS[el * 128 + p * 8] = pmb0;
    *(short8v*)&MS[el * 128 + p * 8 + 64] = pmb1;
    {
      const float* twr = twp + r7 * 128;
      const float* tbr = tbp + r7 * 128;
      f32x4 w0 = *(const f32x4*)(twr + p * 8),      w1 = *(const f32x4*)(twr + p * 8 + 4);
      f32x4 b0 = *(const f32x4*)(tbr + p * 8),      b1 = *(const f32x4*)(tbr + p * 8 + 4);
      f32x4 w2 = *(const f32x4*)(twr + p * 8 + 64), w3 = *(const f32x4*)(twr + p * 8 + 68);
      f32x4 b2 = *(const f32x4*)(tbr + p * 8 + 64), b3 = *(const f32x4*)(tbr + p * 8 + 68);
      short8v ta, tb2;
      #pragma unroll
      for (int j = 0; j < 4; ++j) {
        ta[j]      = f2bf(__cosf(fmaf(prelt, w0[j], b0[j])));
        ta[4 + j]  = f2bf(__cosf(fmaf(prelt, w1[j], b1[j])));
        tb2[j]     = f2bf(__cosf(fmaf(prelt, w2[j], b2[j])));
        tb2[4 + j] = f2bf(__cosf(fmaf(prelt, w3[j], b3[j])));
      }
      *(short8v*)&TEs[el * 128 + p * 8] = ta;
      *(short8v*)&TEs[el * 128 + p * 8 + 64] = tb2;
    }
    __syncthreads();   // barrier A

    // ---- S1: prefetch next tile, MFMA e/k/v, in-register dot -> pdot
    {
      int i = t0 + 64 + el;
      pval = i < end;
      if (pval) {
        int4 m = emeta[i];
        pdst = m.z; prelt = __int_as_float(m.w);
        const unsigned short* xp = xb + (size_t)m.y * 128 + pl * 8;
        px0 = *(const short8v*)xp;
        px1 = *(const short8v*)(xp + 64);
        const float* mp = msg + (size_t)m.x * 128 + pl * 8;
        f32x4 m0 = *(const f32x4*)mp,        m1 = *(const f32x4*)(mp + 4);
        f32x4 m2 = *(const f32x4*)(mp + 64), m3 = *(const f32x4*)(mp + 68);
        #pragma unroll
        for (int j = 0; j < 4; ++j) {
          pmb0[j] = f2bf(m0[j]); pmb0[4 + j] = f2bf(m1[j]);
          pmb1[j] = f2bf(m2[j]); pmb1[4 + j] = f2bf(m3[j]);
        }
      }
    }
    f32x4 ae[4];
    ae[0] = (f32x4){0.f, 0.f, 0.f, 0.f}; ae[1] = ae[0]; ae[2] = ae[0]; ae[3] = ae[0];
    #pragma unroll
    for (int kt = 0; kt < 4; ++kt) {
      const int sw = (((kt << 2) | g) ^ l7) << 3;
      #pragma unroll
      for (int eg = 0; eg < 4; ++eg) {
        const short8v a = *(const short8v*)&TEs[(eg * 16 + lr) * 128 + sw];
        ae[eg] = __builtin_amdgcn_mfma_f32_16x16x32_bf16(a, wef[kt], ae[eg], 0, 0, 0);
      }
    }
    #pragma unroll
    for (int kt = 0; kt < 4; ++kt) {
      const int sw = (((kt << 2) | g) ^ l7) << 3;
      #pragma unroll
      for (int eg = 0; eg < 4; ++eg) {
        const short8v a = *(const short8v*)&MS[(eg * 16 + lr) * 128 + sw];
        ae[eg] = __builtin_amdgcn_mfma_f32_16x16x32_bf16(a, wef[kt + 4], ae[eg], 0, 0, 0);
      }
    }
    {
      f32x4 ak[4];
      ak[0] = (f32x4){0.f, 0.f, 0.f, 0.f}; ak[1] = ak[0]; ak[2] = ak[0]; ak[3] = ak[0];
      #pragma unroll
      for (int kt = 0; kt < 4; ++kt) {
        short8v wkf = *(const short8v*)(Btfrag + (size_t)(((8 + wid) * 4 + kt) * 64 + lane) * 8);
        const int sw = (((kt << 2) | g) ^ l7) << 3;
        #pragma unroll
        for (int eg = 0; eg < 4; ++eg) {
          const short8v a = *(const short8v*)&XS[(eg * 16 + lr) * 128 + sw];
          ak[eg] = __builtin_amdgcn_mfma_f32_16x16x32_bf16(a, wkf, ak[eg], 0, 0, 0);
        }
      }
      float myp = 0.f;
      #pragma unroll
      for (int eg = 0; eg < 4; ++eg)
        #pragma unroll
        for (int rg = 0; rg < 4; ++rg) {
          int row = eg * 16 + g * 4 + rg;
          int dsr = dslot[row];
          int dsx = dsr < 0 ? 0 : dsr;
          float qv = bf2f(QL[dsx * 128 + cme]);
          float t = qv * (ak[eg][rg] + bkc + ae[eg][rg]);
          t += __shfl_xor(t, 1);
          t += __shfl_xor(t, 2);
          t += __shfl_xor(t, 4);
          t += __shfl_xor(t, 8);
          if (((eg << 2) | rg) == lr) myp = t;
        }
      atomicAdd(&pdot[hme * 64 + ((lr >> 2) * 16 + g * 4 + (lr & 3))], myp);
    }
    f32x4 av[4];
    av[0] = (f32x4){0.f, 0.f, 0.f, 0.f}; av[1] = av[0]; av[2] = av[0]; av[3] = av[0];
    #pragma unroll
    for (int kt = 0; kt < 4; ++kt) {
      short8v wvf = *(const short8v*)(Btfrag + (size_t)(((16 + wid) * 4 + kt) * 64 + lane) * 8);
      const int sw = (((kt << 2) | g) ^ l7) << 3;
      #pragma unroll
      for (int eg = 0; eg < 4; ++eg) {
        const short8v a = *(const short8v*)&XS[(eg * 16 + lr) * 128 + sw];
        av[eg] = __builtin_amdgcn_mfma_f32_16x16x32_bf16(a, wvf, av[eg], 0, 0, 0);
      }
    }
    #pragma unroll
    for (int eg = 0; eg < 4; ++eg)
      #pragma unroll
      for (int rg = 0; rg < 4; ++rg)
        av[eg][rg] += bvc + ae[eg][rg];
    __syncthreads();   // barrier B

    // ---- S2: pex = exp(dot/8); accumulate numerator + denominator
    {
      float mypex = 0.f; int mydsr = -1;
      #pragma unroll
      for (int eg = 0; eg < 4; ++eg)
        #pragma unroll
        for (int rg = 0; rg < 4; ++rg) {
          int row = eg * 16 + g * 4 + rg;
          int dsr = dslot[row];
          float pex = __expf(pdot[hme * 64 + row] * 0.125f);
          if (((eg << 2) | rg) == lr) { mypex = pex; mydsr = dsr; }
          if (dsr >= 0) atomicAdd(&accum[dsr * 133 + cme], pex * av[eg][rg]);
        }
      if ((wid & 3) == 0 && mydsr >= 0)
        atomicAdd(&sden[mydsr * 2 + hme], mypex);
    }
    __syncthreads();   // barrier C
  }

  // epilogue: out = skip + bsk + accum / (sden + eps)
  #pragma unroll
  for (int eg = 0; eg < 2; ++eg)
    #pragma unroll
    for (int rg = 0; rg < 4; ++rg) {
      int row = eg * 16 + g * 4 + rg;
      float den = sden[row * 2 + hme] + 1e-16f;
      out[(size_t)(nb0 + row) * 128 + cme] = skacc[eg][rg] + bskc + accum[row * 133 + cme] / den;
    }
}

extern "C" void kernel_launch(void* const* d_in, const int* in_sizes, int n_in,
                              void* d_out, int out_size, void* d_ws, size_t ws_size,
                              hipStream_t stream) {
  const float* x    = (const float*)d_in[0];
  const float* lu   = (const float*)d_in[1];
  const float* tt   = (const float*)d_in[2];
  const float* msg  = (const float*)d_in[3];
  const int*   ei   = (const int*)d_in[4];
  const float* timew = (const float*)d_in[5];
  const float* timeb = (const float*)d_in[6];
  const float* Wq   = (const float*)d_in[7];
  const float* bq   = (const float*)d_in[8];
  const float* Wk   = (const float*)d_in[9];
  const float* bk   = (const float*)d_in[10];
  const float* Wv   = (const float*)d_in[11];
  const float* bv   = (const float*)d_in[12];
  const float* We   = (const float*)d_in[13];
  const float* Wsk  = (const float*)d_in[14];
  const float* bsk  = (const float*)d_in[15];
  float* out = (float*)d_out;

  char* wsp = (char*)d_ws;
  // ws layout (bytes, 16B-aligned), total ~37.0 MB:
  //   [0,          25,600,000)  xb      (N*128 bf16)
  //   [25,600,000, 25,731,072)  Btfrag  (65,536 bf16)
  //   [25,731,072, 25,796,608)  Wefrag  (32,768 bf16)
  //   [25,796,608, 25,800,704)  twp     (8*128 f32)
  //   [25,800,704, 25,804,800)  tbp     (8*128 f32)
  //   [25,804,800, 26,204,800)  cnt     (N i32)
  //   [26,204,800, 26,604,800)  cur     (N i32)
  //   [26,604,800, 27,005,184)  offtmp  (100,096 i32)
  //   [27,005,184, 27,007,232)  bsum    (512 i32)
  //   [27,007,232, 27,009,280)  bbase   (512 i32)
  //   [27,009,280, 29,009,280)  sorted  (E i32)
  //   [29,009,280, 37,009,280)  emeta   (E int4)
  unsigned short* xbw = (unsigned short*)wsp;
  short* Btfrag = (short*)(wsp + 25600000);
  short* Wefrag = (short*)(wsp + 25731072);
  float* twp    = (float*)(wsp + 25796608);
  float* tbp    = (float*)(wsp + 25800704);
  int* cnt      = (int*)(wsp + 25804800);
  int* cur      = (int*)(wsp + 26204800);
  int* offtmp   = (int*)(wsp + 26604800);
  int* bsum     = (int*)(wsp + 27005184);
  int* bbase    = (int*)(wsp + 27007232);
  int* sorted   = (int*)(wsp + 27009280);
  int4* emeta   = (int4*)(wsp + 29009280);

  k_zero<<<782, 256, 0, stream>>>(cnt, 200000);           // cnt + cur
  k_prep<<<392, 256, 0, stream>>>(Wq, Wk, Wv, Wsk, We, timew, timeb,
                                  Btfrag, Wefrag, twp, tbp);
  k_xcast<<<6250, 256, 0, stream>>>(x, xbw);
  k_hist<<<1954, 256, 0, stream>>>(ei, cnt);
  k_scan_a<<<391, 256, 0, stream>>>(cnt, offtmp, bsum);
  k_scan_b<<<1, 512, 0, stream>>>(bsum, bbase);
  k_scatter<<<1954, 256, 0, stream>>>(ei, offtmp, bbase, cur, sorted);
  k_emeta<<<1954, 256, 0, stream>>>(ei, tt, lu, sorted, emeta);
  k_main<<<3125, 512, 0, stream>>>(xbw, msg, twp, tbp,
                                   Btfrag, Wefrag, bq, bk, bv, bsk,
                                   offtmp, bbase, emeta, out);
}

// Round 5
// 783.236 us; speedup vs baseline: 1.0614x; 1.0614x over previous
//
#include <hip/hip_runtime.h>
#include <hip/hip_bf16.h>

#define NN 100000
#define EE 500000

typedef __attribute__((ext_vector_type(8))) short short8v;
typedef __attribute__((ext_vector_type(4))) float f32x4;

__device__ __forceinline__ short f2bf(float f) {
  unsigned u = __builtin_bit_cast(unsigned, f);
  u += 0x7fffu + ((u >> 16) & 1u);
  return (short)(u >> 16);
}
__device__ __forceinline__ float bf2f(short s) {
  unsigned u = ((unsigned)(unsigned short)s) << 16;
  return __builtin_bit_cast(float, u);
}

// ---------------- K0: weights -> bf16 fragment layouts + permuted tw/tb -----
__global__ __launch_bounds__(256) void k_prep(
    const float* __restrict__ Wq, const float* __restrict__ Wk,
    const float* __restrict__ Wv, const float* __restrict__ Wsk,
    const float* __restrict__ We, const float* __restrict__ tw,
    const float* __restrict__ tb,
    short* __restrict__ Btfrag, short* __restrict__ Wefrag,
    float* __restrict__ twp, float* __restrict__ tbp)
{
  int idx = blockIdx.x * 256 + threadIdx.x;
  if (idx < 65536) {
    int b = idx & 7, lane = (idx >> 3) & 63, kt = (idx >> 9) & 3, tn = (idx >> 11) & 7, cb = idx >> 14;
    int k = kt * 32 + (lane >> 4) * 8 + b;
    int c = tn * 16 + (lane & 15);
    const float* W = cb == 0 ? Wq : cb == 1 ? Wk : cb == 2 ? Wv : Wsk;
    Btfrag[idx] = f2bf(W[k * 128 + c]);
  } else if (idx < 98304) {
    int i2 = idx - 65536;
    int b = i2 & 7, lane = (i2 >> 3) & 63, kt = (i2 >> 9) & 7, strip = i2 >> 12;
    int k = kt * 32 + (lane >> 4) * 8 + b;
    int c = strip * 16 + (lane & 15);
    Wefrag[i2] = f2bf(We[k * 128 + c]);
  } else if (idx < 100352) {
    int i3 = idx - 98304;
    int which = i3 >> 10;
    int r = (i3 >> 7) & 7;
    int c = i3 & 127;
    int lc = ((c >> 3) ^ r) * 8 + (c & 7);
    if (which) tbp[r * 128 + c] = tb[lc];
    else       twp[r * 128 + c] = tw[lc];
  }
}

// ---------------- K1: x -> bf16 ---------------------------------------------
__global__ __launch_bounds__(256) void k_xcast(const float* __restrict__ x,
                                               unsigned short* __restrict__ xb)
{
  size_t base = ((size_t)blockIdx.x * 256 + threadIdx.x) * 8;
  f32x4 a = *(const f32x4*)(x + base);
  f32x4 b = *(const f32x4*)(x + base + 4);
  short8v w;
  #pragma unroll
  for (int j = 0; j < 4; ++j) { w[j] = f2bf(a[j]); w[4 + j] = f2bf(b[j]); }
  *(short8v*)(xb + base) = w;
}

__global__ __launch_bounds__(256) void k_zero(int* __restrict__ p, int n)
{
  int i = blockIdx.x * 256 + threadIdx.x;
  if (i < n) p[i] = 0;
}

// ---------------- counting sort by dst --------------------------------------
__global__ __launch_bounds__(256) void k_hist(const int* __restrict__ ei, int* __restrict__ cnt)
{
  int e = blockIdx.x * 256 + threadIdx.x;
  if (e < EE) atomicAdd(&cnt[ei[EE + e]], 1);
}

__global__ __launch_bounds__(256) void k_scan_a(const int* __restrict__ cnt,
    int* __restrict__ offtmp, int* __restrict__ bsum)
{
  __shared__ int sc[256];
  int t = threadIdx.x;
  int i = blockIdx.x * 256 + t;
  int v = (i < NN) ? cnt[i] : 0;
  sc[t] = v;
  __syncthreads();
  for (int d = 1; d < 256; d <<= 1) {
    int add = (t >= d) ? sc[t - d] : 0;
    __syncthreads();
    sc[t] += add;
    __syncthreads();
  }
  if (i < NN) offtmp[i] = sc[t] - v;
  if (t == 255) bsum[blockIdx.x] = sc[255];
}

__global__ __launch_bounds__(512) void k_scan_b(const int* __restrict__ bsum,
                                                int* __restrict__ bbase)
{
  __shared__ int sc[512];
  int t = threadIdx.x;
  int v = (t < 391) ? bsum[t] : 0;
  sc[t] = v;
  __syncthreads();
  for (int d = 1; d < 512; d <<= 1) {
    int add = (t >= d) ? sc[t - d] : 0;
    __syncthreads();
    sc[t] += add;
    __syncthreads();
  }
  bbase[t] = sc[t] - v;
}

__global__ __launch_bounds__(256) void k_scatter(const int* __restrict__ ei,
    const int* __restrict__ offtmp, const int* __restrict__ bbase,
    int* __restrict__ cur, int* __restrict__ sorted)
{
  int e = blockIdx.x * 256 + threadIdx.x;
  if (e < EE) {
    int d = ei[EE + e];
    int pos = offtmp[d] + bbase[d >> 8] + atomicAdd(&cur[d], 1);
    sorted[pos] = e;
  }
}

// ---------------- K_emeta: pack per-edge meta in sorted order ---------------
__global__ __launch_bounds__(256) void k_emeta(const int* __restrict__ ei,
    const float* __restrict__ tt, const float* __restrict__ lu,
    const int* __restrict__ sorted, int4* __restrict__ emeta)
{
  int i = blockIdx.x * 256 + threadIdx.x;
  if (i < EE) {
    int eid = sorted[i];
    int sv = ei[eid];
    int4 m;
    m.x = eid; m.y = sv; m.z = ei[EE + eid];
    m.w = __float_as_int(tt[eid] - lu[sv]);
    emeta[i] = m;
  }
}

// ---------------- K_main: 32 dst nodes/block, 64-edge tiles, swizzled LDS ---
__global__ __launch_bounds__(512) void k_main(
    const unsigned short* __restrict__ xb, const float* __restrict__ msg,
    const float* __restrict__ twp, const float* __restrict__ tbp,
    const short* __restrict__ Btfrag, const short* __restrict__ Wefrag,
    const float* __restrict__ bq, const float* __restrict__ bk,
    const float* __restrict__ bv, const float* __restrict__ bsk,
    const int* __restrict__ offtmp, const int* __restrict__ bbase,
    const int4* __restrict__ emeta, float* __restrict__ out)
{
  __shared__ short XS[64 * 128];    // x[src] bf16, chunk-swizzled rows
  __shared__ short MS[64 * 128];    // msg bf16, swizzled
  __shared__ short TEs[64 * 128];   // time enc bf16, swizzled
  __shared__ short QL[32 * 136];    // q bf16 per owned node (136: bank-spread)
  __shared__ float accum[32 * 133]; // f32 numerator
  __shared__ float pdot[128];       // [head][64 edge rows] raw dot
  __shared__ float sden[64];        // [32 nodes][2 heads]
  __shared__ int dslot[64];

  const int tid = threadIdx.x;
  const int nb0 = blockIdx.x * 32;
  const int wid = tid >> 6, lane = tid & 63;
  const int g = lane >> 4, lr = lane & 15, l7 = lr & 7;
  const int el = tid >> 3, p = tid & 7;
  const int r7 = el & 7;
  const int pl = p ^ r7;             // logical chunk staged by this thread
  const int cme = wid * 16 + lr;     // this wave's output column
  const int hme = wid >> 2;          // head of this wave

  for (int i = tid; i < 32 * 133; i += 512) accum[i] = 0.f;
  if (tid < 64) sden[tid] = 0.f;

  const float bqc = bq[cme], bkc = bk[cme], bvc = bv[cme], bskc = bsk[cme];

  // stage owned nodes' x (rows 0..31), swizzled
  if (el < 32) {
    int node = nb0 + el;
    const unsigned short* xp = xb + (size_t)node * 128;
    short8v a = *(const short8v*)(xp + pl * 8);
    short8v b = *(const short8v*)(xp + pl * 8 + 64);
    *(short8v*)&XS[el * 128 + p * 8] = a;
    *(short8v*)&XS[el * 128 + p * 8 + 64] = b;
  }
  __syncthreads();

  // prologue: q -> QL (bf16), skip -> out (global, re-read at epilogue)
  {
    f32x4 qacc[2], skacc[2];
    qacc[0] = (f32x4){0.f, 0.f, 0.f, 0.f}; qacc[1] = qacc[0];
    skacc[0] = qacc[0]; skacc[1] = qacc[0];
    #pragma unroll
    for (int kt = 0; kt < 4; ++kt) {
      short8v bqf = *(const short8v*)(Btfrag + (size_t)(((0 + wid) * 4 + kt) * 64 + lane) * 8);
      short8v bsf = *(const short8v*)(Btfrag + (size_t)(((24 + wid) * 4 + kt) * 64 + lane) * 8);
      const int sw = (((kt << 2) | g) ^ l7) << 3;
      #pragma unroll
      for (int eg = 0; eg < 2; ++eg) {
        const short8v a = *(const short8v*)&XS[(eg * 16 + lr) * 128 + sw];
        qacc[eg] = __builtin_amdgcn_mfma_f32_16x16x32_bf16(a, bqf, qacc[eg], 0, 0, 0);
        skacc[eg] = __builtin_amdgcn_mfma_f32_16x16x32_bf16(a, bsf, skacc[eg], 0, 0, 0);
      }
    }
    #pragma unroll
    for (int eg = 0; eg < 2; ++eg)
      #pragma unroll
      for (int rg = 0; rg < 4; ++rg) {
        int row = eg * 16 + g * 4 + rg;
        QL[row * 136 + cme] = f2bf(qacc[eg][rg] + bqc);
        out[(size_t)(nb0 + row) * 128 + cme] = skacc[eg][rg] + bskc;
      }
  }

  const int beg = offtmp[nb0] + bbase[nb0 >> 8];
  const int end = (nb0 + 32 < NN) ? (offtmp[nb0 + 32] + bbase[(nb0 + 32) >> 8]) : EE;

  // prefetch tile 0
  int pdst = 0; float prelt = 0.f; bool pval = false;
  short8v px0 = {0,0,0,0,0,0,0,0}, px1 = px0, pmb0 = px0, pmb1 = px0;
  {
    int i = beg + el;
    pval = i < end;
    if (pval) {
      int4 m = emeta[i];
      pdst = m.z; prelt = __int_as_float(m.w);
      const unsigned short* xp = xb + (size_t)m.y * 128 + pl * 8;
      px0 = *(const short8v*)xp;
      px1 = *(const short8v*)(xp + 64);
      const float* mp = msg + (size_t)m.x * 128 + pl * 8;
      f32x4 m0 = *(const f32x4*)mp,        m1 = *(const f32x4*)(mp + 4);
      f32x4 m2 = *(const f32x4*)(mp + 64), m3 = *(const f32x4*)(mp + 68);
      #pragma unroll
      for (int j = 0; j < 4; ++j) {
        pmb0[j] = f2bf(m0[j]); pmb0[4 + j] = f2bf(m1[j]);
        pmb1[j] = f2bf(m2[j]); pmb1[4 + j] = f2bf(m3[j]);
      }
    }
  }
  __syncthreads();   // QL visible; XS free for edge tiles

  for (int t0 = beg; t0 < end; t0 += 64) {
    // ---- S0: commit prefetched tile (swizzled), zero pdot, meta
    if (tid < 128) pdot[tid] = 0.f;
    if (p == 0) dslot[el] = pval ? (pdst - nb0) : -1;
    *(short8v*)&XS[el * 128 + p * 8] = px0;
    *(short8v*)&XS[el * 128 + p * 8 + 64] = px1;
    *(short8v*)&MS[el * 128 + p * 8] = pmb0;
    *(short8v*)&MS[el * 128 + p * 8 + 64] = pmb1;
    {
      const float* twr = twp + r7 * 128;
      const float* tbr = tbp + r7 * 128;
      f32x4 w0 = *(const f32x4*)(twr + p * 8),      w1 = *(const f32x4*)(twr + p * 8 + 4);
      f32x4 b0 = *(const f32x4*)(tbr + p * 8),      b1 = *(const f32x4*)(tbr + p * 8 + 4);
      f32x4 w2 = *(const f32x4*)(twr + p * 8 + 64), w3 = *(const f32x4*)(twr + p * 8 + 68);
      f32x4 b2 = *(const f32x4*)(tbr + p * 8 + 64), b3 = *(const f32x4*)(tbr + p * 8 + 68);
      short8v ta, tb2;
      #pragma unroll
      for (int j = 0; j < 4; ++j) {
        ta[j]      = f2bf(__cosf(fmaf(prelt, w0[j], b0[j])));
        ta[4 + j]  = f2bf(__cosf(fmaf(prelt, w1[j], b1[j])));
        tb2[j]     = f2bf(__cosf(fmaf(prelt, w2[j], b2[j])));
        tb2[4 + j] = f2bf(__cosf(fmaf(prelt, w3[j], b3[j])));
      }
      *(short8v*)&TEs[el * 128 + p * 8] = ta;
      *(short8v*)&TEs[el * 128 + p * 8 + 64] = tb2;
    }
    __syncthreads();   // barrier A

    // ---- S1: prefetch next tile, MFMA e/k/v, dot -> pdot
    {
      int i = t0 + 64 + el;
      pval = i < end;
      if (pval) {
        int4 m = emeta[i];
        pdst = m.z; prelt = __int_as_float(m.w);
        const unsigned short* xp = xb + (size_t)m.y * 128 + pl * 8;
        px0 = *(const short8v*)xp;
        px1 = *(const short8v*)(xp + 64);
        const float* mp = msg + (size_t)m.x * 128 + pl * 8;
        f32x4 m0 = *(const f32x4*)mp,        m1 = *(const f32x4*)(mp + 4);
        f32x4 m2 = *(const f32x4*)(mp + 64), m3 = *(const f32x4*)(mp + 68);
        #pragma unroll
        for (int j = 0; j < 4; ++j) {
          pmb0[j] = f2bf(m0[j]); pmb0[4 + j] = f2bf(m1[j]);
          pmb1[j] = f2bf(m2[j]); pmb1[4 + j] = f2bf(m3[j]);
        }
      }
    }
    f32x4 ae[4];
    ae[0] = (f32x4){0.f, 0.f, 0.f, 0.f}; ae[1] = ae[0]; ae[2] = ae[0]; ae[3] = ae[0];
    #pragma unroll
    for (int kt = 0; kt < 4; ++kt) {
      short8v wef = *(const short8v*)(Wefrag + (size_t)((wid * 8 + kt) * 64 + lane) * 8);
      const int sw = (((kt << 2) | g) ^ l7) << 3;
      #pragma unroll
      for (int eg = 0; eg < 4; ++eg) {
        const short8v a = *(const short8v*)&TEs[(eg * 16 + lr) * 128 + sw];
        ae[eg] = __builtin_amdgcn_mfma_f32_16x16x32_bf16(a, wef, ae[eg], 0, 0, 0);
      }
    }
    #pragma unroll
    for (int kt = 0; kt < 4; ++kt) {
      short8v wef = *(const short8v*)(Wefrag + (size_t)((wid * 8 + kt + 4) * 64 + lane) * 8);
      const int sw = (((kt << 2) | g) ^ l7) << 3;
      #pragma unroll
      for (int eg = 0; eg < 4; ++eg) {
        const short8v a = *(const short8v*)&MS[(eg * 16 + lr) * 128 + sw];
        ae[eg] = __builtin_amdgcn_mfma_f32_16x16x32_bf16(a, wef, ae[eg], 0, 0, 0);
      }
    }
    {
      f32x4 ak[4];
      ak[0] = (f32x4){0.f, 0.f, 0.f, 0.f}; ak[1] = ak[0]; ak[2] = ak[0]; ak[3] = ak[0];
      #pragma unroll
      for (int kt = 0; kt < 4; ++kt) {
        short8v wkf = *(const short8v*)(Btfrag + (size_t)(((8 + wid) * 4 + kt) * 64 + lane) * 8);
        const int sw = (((kt << 2) | g) ^ l7) << 3;
        #pragma unroll
        for (int eg = 0; eg < 4; ++eg) {
          const short8v a = *(const short8v*)&XS[(eg * 16 + lr) * 128 + sw];
          ak[eg] = __builtin_amdgcn_mfma_f32_16x16x32_bf16(a, wkf, ak[eg], 0, 0, 0);
        }
      }
      float myp = 0.f;
      #pragma unroll
      for (int eg = 0; eg < 4; ++eg)
        #pragma unroll
        for (int rg = 0; rg < 4; ++rg) {
          int row = eg * 16 + g * 4 + rg;
          int dsr = dslot[row];
          int dsx = dsr < 0 ? 0 : dsr;
          float qv = bf2f(QL[dsx * 136 + cme]);
          float t = qv * (ak[eg][rg] + bkc + ae[eg][rg]);
          t += __shfl_xor(t, 1);
          t += __shfl_xor(t, 2);
          t += __shfl_xor(t, 4);
          t += __shfl_xor(t, 8);
          if (((eg << 2) | rg) == lr) myp = t;
        }
      atomicAdd(&pdot[hme * 64 + ((lr >> 2) * 16 + g * 4 + (lr & 3))], myp);
    }
    f32x4 av[4];
    av[0] = (f32x4){0.f, 0.f, 0.f, 0.f}; av[1] = av[0]; av[2] = av[0]; av[3] = av[0];
    #pragma unroll
    for (int kt = 0; kt < 4; ++kt) {
      short8v wvf = *(const short8v*)(Btfrag + (size_t)(((16 + wid) * 4 + kt) * 64 + lane) * 8);
      const int sw = (((kt << 2) | g) ^ l7) << 3;
      #pragma unroll
      for (int eg = 0; eg < 4; ++eg) {
        const short8v a = *(const short8v*)&XS[(eg * 16 + lr) * 128 + sw];
        av[eg] = __builtin_amdgcn_mfma_f32_16x16x32_bf16(a, wvf, av[eg], 0, 0, 0);
      }
    }
    #pragma unroll
    for (int eg = 0; eg < 4; ++eg)
      #pragma unroll
      for (int rg = 0; rg < 4; ++rg)
        av[eg][rg] += bvc + ae[eg][rg];
    __syncthreads();   // barrier B

    // ---- S2: pex = exp(dot/8); accumulate numerator + denominator
    {
      float mypex = 0.f; int mydsr = -1;
      #pragma unroll
      for (int eg = 0; eg < 4; ++eg)
        #pragma unroll
        for (int rg = 0; rg < 4; ++rg) {
          int row = eg * 16 + g * 4 + rg;
          int dsr = dslot[row];
          float pex = __expf(pdot[hme * 64 + row] * 0.125f);
          if (((eg << 2) | rg) == lr) { mypex = pex; mydsr = dsr; }
          if (dsr >= 0) atomicAdd(&accum[dsr * 133 + cme], pex * av[eg][rg]);
        }
      if ((wid & 3) == 0 && mydsr >= 0)
        atomicAdd(&sden[mydsr * 2 + hme], mypex);
    }
    __syncthreads();   // barrier C
  }

  // epilogue: out += accum / (sden + eps)   (skip already in out)
  #pragma unroll
  for (int eg = 0; eg < 2; ++eg)
    #pragma unroll
    for (int rg = 0; rg < 4; ++rg) {
      int row = eg * 16 + g * 4 + rg;
      float den = sden[row * 2 + hme] + 1e-16f;
      size_t o = (size_t)(nb0 + row) * 128 + cme;
      out[o] = out[o] + accum[row * 133 + cme] / den;
    }
}

extern "C" void kernel_launch(void* const* d_in, const int* in_sizes, int n_in,
                              void* d_out, int out_size, void* d_ws, size_t ws_size,
                              hipStream_t stream) {
  const float* x    = (const float*)d_in[0];
  const float* lu   = (const float*)d_in[1];
  const float* tt   = (const float*)d_in[2];
  const float* msg  = (const float*)d_in[3];
  const int*   ei   = (const int*)d_in[4];
  const float* timew = (const float*)d_in[5];
  const float* timeb = (const float*)d_in[6];
  const float* Wq   = (const float*)d_in[7];
  const float* bq   = (const float*)d_in[8];
  const float* Wk   = (const float*)d_in[9];
  const float* bk   = (const float*)d_in[10];
  const float* Wv   = (const float*)d_in[11];
  const float* bv   = (const float*)d_in[12];
  const float* We   = (const float*)d_in[13];
  const float* Wsk  = (const float*)d_in[14];
  const float* bsk  = (const float*)d_in[15];
  float* out = (float*)d_out;

  char* wsp = (char*)d_ws;
  unsigned short* xbw = (unsigned short*)wsp;
  short* Btfrag = (short*)(wsp + 25600000);
  short* Wefrag = (short*)(wsp + 25731072);
  float* twp    = (float*)(wsp + 25796608);
  float* tbp    = (float*)(wsp + 25800704);
  int* cnt      = (int*)(wsp + 25804800);
  int* cur      = (int*)(wsp + 26204800);
  int* offtmp   = (int*)(wsp + 26604800);
  int* bsum     = (int*)(wsp + 27005184);
  int* bbase    = (int*)(wsp + 27007232);
  int* sorted   = (int*)(wsp + 27009280);
  int4* emeta   = (int4*)(wsp + 29009280);

  k_zero<<<782, 256, 0, stream>>>(cnt, 200000);           // cnt + cur
  k_prep<<<392, 256, 0, stream>>>(Wq, Wk, Wv, Wsk, We, timew, timeb,
                                  Btfrag, Wefrag, twp, tbp);
  k_xcast<<<6250, 256, 0, stream>>>(x, xbw);
  k_hist<<<1954, 256, 0, stream>>>(ei, cnt);
  k_scan_a<<<391, 256, 0, stream>>>(cnt, offtmp, bsum);
  k_scan_b<<<1, 512, 0, stream>>>(bsum, bbase);
  k_scatter<<<1954, 256, 0, stream>>>(ei, offtmp, bbase, cur, sorted);
  k_emeta<<<1954, 256, 0, stream>>>(ei, tt, lu, sorted, emeta);
  k_main<<<3125, 512, 0, stream>>>(xbw, msg, twp, tbp,
                                   Btfrag, Wefrag, bq, bk, bv, bsk,
                                   offtmp, bbase, emeta, out);
}